// Round 1
// baseline (3202.590 us; speedup 1.0000x reference)
//
#include <hip/hip_runtime.h>
#include <cmath>

// Problem constants (fixed by the dataset).
constexpr int N = 16384;   // rows
constexpr int D = 256;     // half feature dim
constexpr int K = 512;     // 2D
constexpr int V = 8192;    // codebook size

// Pass-1 tiling.
constexpr int BN = 64;     // rows per block
constexpr int BV = 128;    // codes per v-tile
constexpr int BK = 64;     // k chunk
constexpr int ZS_STRIDE = 68;  // padded (2-way LDS conflicts max, 16B-aligned rows)
constexpr float TAU = 1e-3f;   // near-tie margin -> fp64 rescore (fp32 noise ~5e-6)

// ---------------------------------------------------------------- w2 = ||w||^2
__global__ __launch_bounds__(256) void vq_w2(const float* __restrict__ w,
                                             double* __restrict__ w2d,
                                             float* __restrict__ w2f) {
  int v = blockIdx.x * 4 + (threadIdx.x >> 6);
  int lane = threadIdx.x & 63;
  const float4* wr = (const float4*)(w + (size_t)v * K);
  float4 a = wr[lane];
  float4 b = wr[64 + lane];
  double s = (double)a.x * a.x + (double)a.y * a.y + (double)a.z * a.z + (double)a.w * a.w +
             (double)b.x * b.x + (double)b.y * b.y + (double)b.z * b.z + (double)b.w * b.w;
#pragma unroll
  for (int off = 1; off < 64; off <<= 1) s += __shfl_xor(s, off, 64);
  if (lane == 0) {
    w2d[v] = s;
    w2f[v] = (float)s;
  }
}

// ------------------------------------------- pass 1: fp32 GEMM + top-2 argmin
__global__ __launch_bounds__(256) void vq_pass1(
    const float* __restrict__ zr, const float* __restrict__ zi,
    const float* __restrict__ w, const float* __restrict__ w2f,
    float* __restrict__ out_idx, int* __restrict__ ws_idx,
    int* __restrict__ flaglist, int* __restrict__ nflag) {
  __shared__ float zs[BN * ZS_STRIDE];  // [n][k], stride 68
  __shared__ float wsm[BV * BK];        // [v][k], float4-XOR-swizzled on k by (v&15)

  const int tid = threadIdx.x;
  const int tx = tid & 15;        // col group
  const int ty = tid >> 4;        // row group (0..15)
  const int rowBase = blockIdx.x * BN;

  float min1[4], min2[4];
  int idx1[4];
#pragma unroll
  for (int i = 0; i < 4; ++i) {
    min1[i] = 3.4e38f;
    min2[i] = 3.4e38f;
    idx1[i] = 0;
  }

  for (int vt = 0; vt < V; vt += BV) {
    float acc[4][8];
#pragma unroll
    for (int i = 0; i < 4; ++i)
#pragma unroll
      for (int j = 0; j < 8; ++j) acc[i][j] = 0.f;

    for (int kt = 0; kt < K; kt += BK) {
      __syncthreads();  // protect LDS from previous tile's readers
      // stage z tile: 64 rows x 64 k  (z_flat = [zr | zi], BK divides D)
      const float* zbase = (kt < D) ? zr + kt : zi + (kt - D);
#pragma unroll
      for (int m = 0; m < 4; ++m) {
        int lin = tid + m * 256;
        int rl = lin >> 4, c4 = lin & 15;
        float4 zv = *(const float4*)(zbase + (size_t)(rowBase + rl) * D + 4 * c4);
        *(float4*)&zs[rl * ZS_STRIDE + 4 * c4] = zv;
      }
      // stage w tile: 128 rows x 64 k, swizzled
#pragma unroll
      for (int m = 0; m < 8; ++m) {
        int lin = tid + m * 256;
        int rl = lin >> 4, c4 = lin & 15;
        float4 wv = *(const float4*)(w + (size_t)(vt + rl) * K + kt + 4 * c4);
        *(float4*)&wsm[rl * BK + ((c4 ^ (rl & 15)) << 2)] = wv;
      }
      __syncthreads();

      for (int kk4 = 0; kk4 < 16; ++kk4) {
        float4 av[4], bv[8];
#pragma unroll
        for (int i = 0; i < 4; ++i)
          av[i] = *(const float4*)&zs[(ty * 4 + i) * ZS_STRIDE + 4 * kk4];
#pragma unroll
        for (int j = 0; j < 8; ++j) {
          int c = tx + 16 * j;  // c & 15 == tx -> full bank spread
          bv[j] = *(const float4*)&wsm[c * BK + ((kk4 ^ tx) << 2)];
        }
#pragma unroll
        for (int i = 0; i < 4; ++i)
#pragma unroll
          for (int j = 0; j < 8; ++j) {
            acc[i][j] = fmaf(av[i].x, bv[j].x, acc[i][j]);
            acc[i][j] = fmaf(av[i].y, bv[j].y, acc[i][j]);
            acc[i][j] = fmaf(av[i].z, bv[j].z, acc[i][j]);
            acc[i][j] = fmaf(av[i].w, bv[j].w, acc[i][j]);
          }
      }
    }

    // epilogue: scores + top-2 update (v ascending per thread)
#pragma unroll
    for (int j = 0; j < 8; ++j) {
      int v = vt + tx + 16 * j;
      float w2v = w2f[v];
#pragma unroll
      for (int i = 0; i < 4; ++i) {
        float s = fmaf(-2.0f, acc[i][j], w2v);
        if (s < min1[i]) {
          min2[i] = min1[i];
          min1[i] = s;
          idx1[i] = v;
        } else if (s < min2[i]) {
          min2[i] = s;
        }
      }
    }
  }

  // reduce across the 16 tx-lanes sharing each row
#pragma unroll
  for (int i = 0; i < 4; ++i) {
    float m1 = min1[i], m2 = min2[i];
    int ix = idx1[i];
#pragma unroll
    for (int off = 1; off < 16; off <<= 1) {
      float om1 = __shfl_xor(m1, off, 64);
      float om2 = __shfl_xor(m2, off, 64);
      int oix = __shfl_xor(ix, off, 64);
      float nm2 = fminf(fmaxf(m1, om1), fminf(m2, om2));
      bool take = (om1 < m1) || (om1 == m1 && oix < ix);
      if (take) {
        m1 = om1;
        ix = oix;
      }
      m2 = nm2;
    }
    if (tx == 0) {
      int row = rowBase + ty * 4 + i;
      out_idx[row] = (float)ix;
      ws_idx[row] = ix;
      if (m2 - m1 < TAU) {
        int slot = atomicAdd(nflag, 1);
        flaglist[slot] = row;
      }
    }
  }
}

// ------------------------- pass 2: exact fp64 rescore for near-tie rows only
__global__ __launch_bounds__(256) void vq_fixup(
    const float* __restrict__ zr, const float* __restrict__ zi,
    const float* __restrict__ w, const double* __restrict__ w2d,
    const int* __restrict__ flaglist, const int* __restrict__ nflag,
    float* __restrict__ out_idx, int* __restrict__ ws_idx) {
  __shared__ float zl[K];
  __shared__ double smin[256];
  __shared__ int sidx[256];
  const int tid = threadIdx.x;
  const int nf = *nflag;

  for (int f = blockIdx.x; f < nf; f += gridDim.x) {
    int row = flaglist[f];
    __syncthreads();
    for (int k = tid; k < K; k += 256)
      zl[k] = (k < D) ? zr[(size_t)row * D + k] : zi[(size_t)row * D + (k - D)];
    __syncthreads();

    double best = 1e300;
    int bidx = 0;
    for (int v = tid; v < V; v += 256) {
      const float4* wr4 = (const float4*)(w + (size_t)v * K);
      const float4* zl4 = (const float4*)zl;
      double dot = 0.0;
      for (int k4 = 0; k4 < K / 4; ++k4) {
        float4 a = wr4[k4];
        float4 b = zl4[k4];
        dot = fma((double)a.x, (double)b.x, dot);
        dot = fma((double)a.y, (double)b.y, dot);
        dot = fma((double)a.z, (double)b.z, dot);
        dot = fma((double)a.w, (double)b.w, dot);
      }
      double d = w2d[v] - 2.0 * dot;
      if (d < best) {  // v ascending -> strict keeps smallest index on ties
        best = d;
        bidx = v;
      }
    }
    smin[tid] = best;
    sidx[tid] = bidx;
    __syncthreads();
    for (int s = 128; s > 0; s >>= 1) {
      if (tid < s) {
        if (smin[tid + s] < smin[tid] ||
            (smin[tid + s] == smin[tid] && sidx[tid + s] < sidx[tid])) {
          smin[tid] = smin[tid + s];
          sidx[tid] = sidx[tid + s];
        }
      }
      __syncthreads();
    }
    if (tid == 0) {
      out_idx[row] = (float)sidx[0];
      ws_idx[row] = sidx[0];
    }
  }
}

// ---------------- gather z_q, write outputs 0/1, loss, histogram for entropy
__global__ __launch_bounds__(256) void vq_gather(
    const float* __restrict__ zr, const float* __restrict__ zi,
    const float* __restrict__ w, const int* __restrict__ ws_idx,
    float* __restrict__ out0, float* __restrict__ out1,
    float* __restrict__ out2, unsigned int* __restrict__ counts) {
  int row = blockIdx.x * 4 + (threadIdx.x >> 6);
  int lane = threadIdx.x & 63;
  int idx = ws_idx[row];
  const float4* wr = (const float4*)(w + (size_t)idx * K);
  float4 q0 = wr[lane];        // k = 4*lane
  float4 q1 = wr[64 + lane];   // k = 256 + 4*lane
  float4 a = ((const float4*)(zr + (size_t)row * D))[lane];
  float4 b = ((const float4*)(zi + (size_t)row * D))[lane];
  ((float4*)(out0 + (size_t)row * D))[lane] = q0;
  ((float4*)(out1 + (size_t)row * D))[lane] = q1;

  float s = 0.f, dx;
  dx = q0.x - a.x; s = fmaf(dx, dx, s);
  dx = q0.y - a.y; s = fmaf(dx, dx, s);
  dx = q0.z - a.z; s = fmaf(dx, dx, s);
  dx = q0.w - a.w; s = fmaf(dx, dx, s);
  dx = q1.x - b.x; s = fmaf(dx, dx, s);
  dx = q1.y - b.y; s = fmaf(dx, dx, s);
  dx = q1.z - b.z; s = fmaf(dx, dx, s);
  dx = q1.w - b.w; s = fmaf(dx, dx, s);
#pragma unroll
  for (int off = 1; off < 64; off <<= 1) s += __shfl_xor(s, off, 64);
  if (lane == 0) {
    out2[row] = s * (1.25f / 512.f);  // mean + 0.25*mean over 512 features
    atomicAdd(counts + idx, 1u);
  }
}

// ------------------------------------------------------------------- entropy
__global__ __launch_bounds__(256) void vq_entropy(const unsigned int* __restrict__ counts,
                                                  float* __restrict__ out4) {
  __shared__ double sd[256];
  int tid = threadIdx.x;
  double e = 0.0;
  for (int v = tid; v < V; v += 256) {
    double p = (double)counts[v] * (1.0 / (double)N);
    e += p * log(p + 1e-10);
  }
  sd[tid] = e;
  __syncthreads();
  for (int s = 128; s > 0; s >>= 1) {
    if (tid < s) sd[tid] += sd[tid + s];
    __syncthreads();
  }
  if (tid == 0) *out4 = -(float)sd[0];
}

// ---------------------------------------------------------------------------
extern "C" void kernel_launch(void* const* d_in, const int* in_sizes, int n_in,
                              void* d_out, int out_size, void* d_ws, size_t ws_size,
                              hipStream_t stream) {
  const float* zr = (const float*)d_in[0];
  const float* zi = (const float*)d_in[1];
  const float* w = (const float*)d_in[2];

  float* out = (float*)d_out;
  float* out0 = out;                       // z_q real   (N*D)
  float* out1 = out + (size_t)N * D;       // z_q imag   (N*D)
  float* out2 = out + (size_t)2 * N * D;   // loss       (N)
  float* out3 = out2 + N;                  // indices    (N, as float)
  float* out4 = out3 + N;                  // entropy    (1)

  char* ws = (char*)d_ws;
  double* w2d = (double*)ws;                       // 8192 * 8  = 64 KiB
  float* w2f = (float*)(ws + 65536);               // 8192 * 4  = 32 KiB
  unsigned int* counts = (unsigned int*)(ws + 98304);  // 8192 * 4
  int* ws_idx = (int*)(ws + 131072);               // 16384 * 4
  int* flaglist = (int*)(ws + 196608);             // 16384 * 4
  int* nflag = (int*)(ws + 262144);                // 4

  hipMemsetAsync(counts, 0, V * sizeof(unsigned int), stream);
  hipMemsetAsync(nflag, 0, sizeof(int), stream);

  vq_w2<<<V / 4, 256, 0, stream>>>(w, w2d, w2f);
  vq_pass1<<<N / BN, 256, 0, stream>>>(zr, zi, w, w2f, out3, ws_idx, flaglist, nflag);
  vq_fixup<<<128, 256, 0, stream>>>(zr, zi, w, w2d, flaglist, nflag, out3, ws_idx);
  vq_gather<<<N / 4, 256, 0, stream>>>(zr, zi, w, ws_idx, out0, out1, out2, counts);
  vq_entropy<<<1, 256, 0, stream>>>(counts, out4);
}